// Round 3
// baseline (755.977 us; speedup 1.0000x reference)
//
#include <hip/hip_runtime.h>

#define THREADS 256

// d_out is a FLOAT32 buffer (harness reads np.float32). Integer outputs
// (offsets, idx_values, idx_keys) must be written as numeric floats.
// idx < 2^20 and offsets <= 2^24 are exactly representable in f32.

// ---------------------------------------------------------------------------
// lower_bound fallback on packed pairs — exact searchsorted semantics
// ---------------------------------------------------------------------------
__device__ __forceinline__ int lower_bound_pairs(const int2* __restrict__ a, int n, int x) {
    int lo = 0, hi = n;
    while (lo < hi) {
        int mid = (lo + hi) >> 1;
        if (a[mid].x < x) lo = mid + 1; else hi = mid;
    }
    return lo;
}

__device__ __forceinline__ int lower_bound_arr(const int* __restrict__ a, int n, int x) {
    int lo = 0, hi = n;
    while (lo < hi) {
        int mid = (lo + hi) >> 1;
        if (a[mid] < x) lo = mid + 1; else hi = mid;
    }
    return lo;
}

// ---------------------------------------------------------------------------
// Pack (sorted_ids[i], mapped_idx[i]) -> pairs[i]: the hot remap then does ONE
// 8B gather (single cache line touch) instead of two 4B gathers.
// ---------------------------------------------------------------------------
__global__ void build_pairs(const int* __restrict__ sids, const int* __restrict__ midx,
                            int2* __restrict__ pairs, int V) {
    int i = blockIdx.x * blockDim.x + threadIdx.x;
    int stride = gridDim.x * blockDim.x;
    for (; i < V; i += stride)
        pairs[i] = make_int2(sids[i], midx[i]);
}

// ---------------------------------------------------------------------------
// remap one id: interpolation guess (exact for affine key sets), verify,
// +/-1 probes, then full binary search. Clamp like JAX gather on pos==V.
// ---------------------------------------------------------------------------
template <bool USE_PAIRS>
__device__ __forceinline__ int remap_one(int x,
                                         const int* __restrict__ sids,
                                         const int* __restrict__ midx,
                                         const int2* __restrict__ pairs,
                                         int V, int s0, double scale) {
    double d = (double)((long long)x - (long long)s0);
    int g = (int)(d * scale + 0.5);
    g = max(0, min(V - 1, g));
    if (USE_PAIRS) {
        int2 p = pairs[g];
        if (p.x == x) return p.y;
        if (g + 1 < V) { int2 q = pairs[g + 1]; if (q.x == x) return q.y; }
        if (g > 0)     { int2 q = pairs[g - 1]; if (q.x == x) return q.y; }
        int pos = lower_bound_pairs(pairs, V, x);
        if (pos >= V) pos = V - 1;          // JAX gather clamps OOB indices
        return pairs[pos].y;
    } else {
        if (sids[g] == x) return midx[g];
        if (g + 1 < V && sids[g + 1] == x) return midx[g + 1];
        if (g > 0 && sids[g - 1] == x)     return midx[g - 1];
        int pos = lower_bound_arr(sids, V, x);
        if (pos >= V) pos = V - 1;
        return midx[pos];
    }
}

// ---------------------------------------------------------------------------
// Main fused kernel: per element i
//   out_vals[i] = (float)remap(raw_values[i])
//   out_keys[i] = (float)remap(raw_keys[i])
//   out_wts[i]  = scores[i]   (float bit copy)
// Streaming accesses are lane-contiguous dwords (coalesced).
// ---------------------------------------------------------------------------
template <bool USE_PAIRS>
__global__ void remap_main(const int* __restrict__ rv, const int* __restrict__ rk,
                           const float* __restrict__ sc,
                           const int* __restrict__ sids, const int* __restrict__ midx,
                           const int2* __restrict__ pairs,
                           float* __restrict__ out_vals, float* __restrict__ out_keys,
                           float* __restrict__ out_wts, int N, int V) {
    int s0 = sids[0];
    long long range = (long long)sids[V - 1] - (long long)s0;
    double scale = (range > 0) ? ((double)(V - 1) / (double)range) : 0.0;

    int i = blockIdx.x * blockDim.x + threadIdx.x;
    int stride = gridDim.x * blockDim.x;
    for (; i < N; i += stride) {
        int xv = rv[i];
        int xk = rk[i];
        float w = sc[i];
        out_vals[i] = (float)remap_one<USE_PAIRS>(xv, sids, midx, pairs, V, s0, scale);
        out_keys[i] = (float)remap_one<USE_PAIRS>(xk, sids, midx, pairs, V, s0, scale);
        out_wts[i]  = w;
    }
}

__global__ void copy_offsets(const int* __restrict__ off, float* __restrict__ o1,
                             float* __restrict__ o2, int n) {
    int i = blockIdx.x * blockDim.x + threadIdx.x;
    if (i < n) {
        float v = (float)off[i];
        o1[i] = v;
        o2[i] = v;
    }
}

extern "C" void kernel_launch(void* const* d_in, const int* in_sizes, int n_in,
                              void* d_out, int out_size, void* d_ws, size_t ws_size,
                              hipStream_t stream) {
    const int*   rv   = (const int*)d_in[0];   // raw_values  (N)
    const int*   rk   = (const int*)d_in[1];   // raw_keys    (N)
    const float* sc   = (const float*)d_in[2]; // scores      (N, f32)
    const int*   off  = (const int*)d_in[3];   // offsets     (B+1)
    const int*   sids = (const int*)d_in[4];   // sorted_ids  (V)
    const int*   midx = (const int*)d_in[5];   // mapped_idx  (V)

    const int N    = in_sizes[0];
    const int Boff = in_sizes[3];              // B + 1
    const int V    = in_sizes[4];

    // Output tuple layout (flat float32 words):
    // [offsets | idx_values | offsets | idx_keys | weights]
    float* out    = (float*)d_out;
    float* o_off1 = out;
    float* o_vals = out + Boff;
    float* o_off2 = out + Boff + N;
    float* o_keys = out + 2 * Boff + N;
    float* o_wts  = out + 2 * Boff + 2 * N;

    const bool use_pairs = (ws_size >= (size_t)V * sizeof(int2));
    int2* pairs = (int2*)d_ws;

    if (use_pairs) {
        int blocks = (V + THREADS - 1) / THREADS;
        if (blocks > 2048) blocks = 2048;
        build_pairs<<<blocks, THREADS, 0, stream>>>(sids, midx, pairs, V);
    }

    const int blocks = 4096;
    if (use_pairs) {
        remap_main<true><<<blocks, THREADS, 0, stream>>>(rv, rk, sc, sids, midx, pairs,
                                                         o_vals, o_keys, o_wts, N, V);
    } else {
        remap_main<false><<<blocks, THREADS, 0, stream>>>(rv, rk, sc, sids, midx, pairs,
                                                          o_vals, o_keys, o_wts, N, V);
    }

    copy_offsets<<<(Boff + THREADS - 1) / THREADS, THREADS, 0, stream>>>(off, o_off1, o_off2, Boff);
}

// Round 5
// 508.868 us; speedup vs baseline: 1.4856x; 1.4856x over previous
//
#include <hip/hip_runtime.h>

#define THREADS 256

// d_out is a FLOAT32 buffer: integer outputs written as numeric floats
// (idx < 2^20, offsets <= 2^24 — exactly representable).

__device__ __forceinline__ int lower_bound_arr(const int* __restrict__ a, int n, int x) {
    int lo = 0, hi = n;
    while (lo < hi) {
        int mid = (lo + hi) >> 1;
        if (a[mid] < x) lo = mid + 1; else hi = mid;
    }
    return lo;
}

// Cold path: exact searchsorted + JAX clamp + gather.
__device__ __noinline__ int cold_lookup(int x, const int* __restrict__ sids,
                                        const int* __restrict__ midx, int V) {
    int p = lower_bound_arr(sids, V, x);
    if (p >= V) p = V - 1;
    return midx[p];
}

// ---------------------------------------------------------------------------
// Prologue: verify sids[i] == s0 + i*step for ALL i (exact global affinity).
// On any violation set *flag = 1. ws flag is zeroed by hipMemsetAsync first.
// ---------------------------------------------------------------------------
__global__ void check_affine(const int* __restrict__ sids, int V, int* __restrict__ flag) {
    if (V < 2) { if (blockIdx.x == 0 && threadIdx.x == 0) *flag = 1; return; }
    long long s0 = sids[0], sL = sids[V - 1];
    long long num = sL - s0;
    if (num <= 0 || (num % (long long)(V - 1)) != 0) {
        if (blockIdx.x == 0 && threadIdx.x == 0) *flag = 1;
        return;
    }
    int step = (int)(num / (long long)(V - 1));
    int i = blockIdx.x * blockDim.x + threadIdx.x;
    int stride = gridDim.x * blockDim.x;
    for (; i < V; i += stride) {
        if (sids[i] != (int)(s0 + (long long)i * (long long)step)) { *flag = 1; return; }
    }
}

// Affine-path guess: exact for multiples of step (double keeps error << 0.5).
__device__ __forceinline__ int aff_guess(int x, int s0, double inv_step, int V) {
    int dx = x - s0;
    int g = (int)((double)dx * inv_step + 0.5);
    return max(0, min(V - 1, g));
}

// Fallback (non-affine table) scalar remap: guess + probes + binary search.
__device__ __forceinline__ int remap_general(int x, const int* __restrict__ sids,
                                             const int* __restrict__ midx,
                                             int V, int s0, double scale) {
    double d = (double)((long long)x - (long long)s0);
    int g = (int)(d * scale + 0.5);
    g = max(0, min(V - 1, g));
    if (sids[g] == x) return midx[g];
    if (g + 1 < V && sids[g + 1] == x) return midx[g + 1];
    if (g > 0 && sids[g - 1] == x)     return midx[g - 1];
    return cold_lookup(x, sids, midx, V);
}

// ---------------------------------------------------------------------------
// Main kernel. Affine path: per 4-element chunk, compute 8 positions
// arithmetically, issue 8 independent 4B gathers into the 4MB (L2-resident)
// midx table back-to-back, then verify arithmetically (no memory) and fix
// rare misses via cold path (execz-skipped when all lanes hit).
// ---------------------------------------------------------------------------
__global__ void remap_main(const int* __restrict__ rv, const int* __restrict__ rk,
                           const int* __restrict__ sc,
                           const int* __restrict__ sids, const int* __restrict__ midx,
                           const int* __restrict__ flagp,
                           float* __restrict__ out_vals, float* __restrict__ out_keys,
                           float* __restrict__ out_wts, int N, int V) {
    const int s0 = sids[0];
    const int sL = sids[V - 1];
    const long long range = (long long)sL - (long long)s0;
    const int affine = (*flagp == 0);
    const int step = (affine && V > 1) ? (int)(range / (long long)(V - 1)) : 1;
    const double inv_step = 1.0 / (double)step;
    const double scale = (range > 0) ? ((double)(V - 1) / (double)range) : 0.0;

    const int t = blockIdx.x * blockDim.x + threadIdx.x;
    const int T = gridDim.x * blockDim.x;
    const int N4 = N >> 2;

    if (affine) {
        const int4* __restrict__ rv4 = (const int4*)rv;
        const int4* __restrict__ rk4 = (const int4*)rk;
        const int4* __restrict__ sc4 = (const int4*)sc;
        for (int idx = t; idx < N4; idx += T) {
            int4 v = rv4[idx];
            int4 k = rk4[idx];
            int4 w = sc4[idx];
            // 8 positions (register-only)
            int pv0 = aff_guess(v.x, s0, inv_step, V);
            int pv1 = aff_guess(v.y, s0, inv_step, V);
            int pv2 = aff_guess(v.z, s0, inv_step, V);
            int pv3 = aff_guess(v.w, s0, inv_step, V);
            int pk0 = aff_guess(k.x, s0, inv_step, V);
            int pk1 = aff_guess(k.y, s0, inv_step, V);
            int pk2 = aff_guess(k.z, s0, inv_step, V);
            int pk3 = aff_guess(k.w, s0, inv_step, V);
            // 8 independent gathers, issued before any consumption
            int m0 = midx[pv0];
            int m1 = midx[pv1];
            int m2 = midx[pv2];
            int m3 = midx[pv3];
            int n0 = midx[pk0];
            int n1 = midx[pk1];
            int n2 = midx[pk2];
            int n3 = midx[pk3];
            // arithmetic verify; cold fix is never taken for all-hit input
            if (v.x != s0 + pv0 * step) m0 = cold_lookup(v.x, sids, midx, V);
            if (v.y != s0 + pv1 * step) m1 = cold_lookup(v.y, sids, midx, V);
            if (v.z != s0 + pv2 * step) m2 = cold_lookup(v.z, sids, midx, V);
            if (v.w != s0 + pv3 * step) m3 = cold_lookup(v.w, sids, midx, V);
            if (k.x != s0 + pk0 * step) n0 = cold_lookup(k.x, sids, midx, V);
            if (k.y != s0 + pk1 * step) n1 = cold_lookup(k.y, sids, midx, V);
            if (k.z != s0 + pk2 * step) n2 = cold_lookup(k.z, sids, midx, V);
            if (k.w != s0 + pk3 * step) n3 = cold_lookup(k.w, sids, midx, V);

            const int base = idx << 2;
            out_vals[base + 0] = (float)m0;
            out_vals[base + 1] = (float)m1;
            out_vals[base + 2] = (float)m2;
            out_vals[base + 3] = (float)m3;
            out_keys[base + 0] = (float)n0;
            out_keys[base + 1] = (float)n1;
            out_keys[base + 2] = (float)n2;
            out_keys[base + 3] = (float)n3;
            out_wts[base + 0] = __int_as_float(w.x);
            out_wts[base + 1] = __int_as_float(w.y);
            out_wts[base + 2] = __int_as_float(w.z);
            out_wts[base + 3] = __int_as_float(w.w);
        }
        // tail (N % 4 != 0) — scalar
        for (int i = (N4 << 2) + t; i < N; i += T) {
            int x = rv[i], y = rk[i], wv = sc[i];
            int p = aff_guess(x, s0, inv_step, V);
            int q = aff_guess(y, s0, inv_step, V);
            int m = (x == s0 + p * step) ? midx[p] : cold_lookup(x, sids, midx, V);
            int n = (y == s0 + q * step) ? midx[q] : cold_lookup(y, sids, midx, V);
            out_vals[i] = (float)m;
            out_keys[i] = (float)n;
            out_wts[i]  = __int_as_float(wv);
        }
    } else {
        // general sorted table — exact semantics, scalar
        for (int i = t; i < N; i += T) {
            int x = rv[i], y = rk[i], wv = sc[i];
            out_vals[i] = (float)remap_general(x, sids, midx, V, s0, scale);
            out_keys[i] = (float)remap_general(y, sids, midx, V, s0, scale);
            out_wts[i]  = __int_as_float(wv);
        }
    }
}

__global__ void copy_offsets(const int* __restrict__ off, float* __restrict__ o1,
                             float* __restrict__ o2, int n) {
    int i = blockIdx.x * blockDim.x + threadIdx.x;
    if (i < n) {
        float v = (float)off[i];
        o1[i] = v;
        o2[i] = v;
    }
}

extern "C" void kernel_launch(void* const* d_in, const int* in_sizes, int n_in,
                              void* d_out, int out_size, void* d_ws, size_t ws_size,
                              hipStream_t stream) {
    const int* rv   = (const int*)d_in[0];   // raw_values  (N)
    const int* rk   = (const int*)d_in[1];   // raw_keys    (N)
    const int* sc   = (const int*)d_in[2];   // scores      (N, f32 bits)
    const int* off  = (const int*)d_in[3];   // offsets     (B+1)
    const int* sids = (const int*)d_in[4];   // sorted_ids  (V)
    const int* midx = (const int*)d_in[5];   // mapped_idx  (V)

    const int N    = in_sizes[0];
    const int Boff = in_sizes[3];            // B + 1
    const int V    = in_sizes[4];

    // Output tuple layout (flat f32 words):
    // [offsets | idx_values | offsets | idx_keys | weights]
    float* out    = (float*)d_out;
    float* o_off1 = out;
    float* o_vals = out + Boff;
    float* o_off2 = out + Boff + N;
    float* o_keys = out + 2 * Boff + N;
    float* o_wts  = out + 2 * Boff + 2 * N;

    int* flag = (int*)d_ws;                  // ws[0]: 0 = affine, 1 = not
    hipMemsetAsync(flag, 0, sizeof(int), stream);
    check_affine<<<1024, THREADS, 0, stream>>>(sids, V, flag);

    remap_main<<<4096, THREADS, 0, stream>>>(rv, rk, sc, sids, midx, flag,
                                             o_vals, o_keys, o_wts, N, V);

    copy_offsets<<<(Boff + THREADS - 1) / THREADS, THREADS, 0, stream>>>(off, o_off1, o_off2, Boff);
}

// Round 8
// 490.161 us; speedup vs baseline: 1.5423x; 1.0382x over previous
//
#include <hip/hip_runtime.h>

#define THREADS 256

// Native Clang vector type: __builtin_nontemporal_load requires a true
// vector type (HIP's int4 is a class and is rejected).
typedef int iv4 __attribute__((ext_vector_type(4)));

// d_out is a FLOAT32 buffer: integer outputs written as numeric floats
// (idx < 2^20, offsets <= 2^24 — exactly representable).

__device__ __forceinline__ int lower_bound_arr(const int* __restrict__ a, int n, int x) {
    int lo = 0, hi = n;
    while (lo < hi) {
        int mid = (lo + hi) >> 1;
        if (a[mid] < x) lo = mid + 1; else hi = mid;
    }
    return lo;
}

// Cold path: exact searchsorted + JAX clamp + gather.
__device__ __noinline__ int cold_lookup(int x, const int* __restrict__ sids,
                                        const int* __restrict__ midx, int V) {
    int p = lower_bound_arr(sids, V, x);
    if (p >= V) p = V - 1;
    return midx[p];
}

// ---------------------------------------------------------------------------
// Prologue: verify sids[i] == s0 + i*step for ALL i (exact global affinity).
// ---------------------------------------------------------------------------
__global__ void check_affine(const int* __restrict__ sids, int V, int* __restrict__ flag) {
    if (V < 2) { if (blockIdx.x == 0 && threadIdx.x == 0) *flag = 1; return; }
    long long s0 = sids[0], sL = sids[V - 1];
    long long num = sL - s0;
    if (num <= 0 || (num % (long long)(V - 1)) != 0) {
        if (blockIdx.x == 0 && threadIdx.x == 0) *flag = 1;
        return;
    }
    int step = (int)(num / (long long)(V - 1));
    int i = blockIdx.x * blockDim.x + threadIdx.x;
    int stride = gridDim.x * blockDim.x;
    for (; i < V; i += stride) {
        if (sids[i] != (int)(s0 + (long long)i * (long long)step)) { *flag = 1; return; }
    }
}

// Affine-path guess: exact for multiples of step (double keeps error << 0.5).
__device__ __forceinline__ int aff_guess(int x, int s0, double inv_step, int V) {
    int dx = x - s0;
    int g = (int)((double)dx * inv_step + 0.5);
    return max(0, min(V - 1, g));
}

// Fallback (non-affine table) scalar remap: guess + probes + binary search.
__device__ __forceinline__ int remap_general(int x, const int* __restrict__ sids,
                                             const int* __restrict__ midx,
                                             int V, int s0, double scale) {
    double d = (double)((long long)x - (long long)s0);
    int g = (int)(d * scale + 0.5);
    g = max(0, min(V - 1, g));
    if (sids[g] == x) return midx[g];
    if (g + 1 < V && sids[g + 1] == x) return midx[g + 1];
    if (g > 0 && sids[g - 1] == x)     return midx[g - 1];
    return cold_lookup(x, sids, midx, V);
}

// ---------------------------------------------------------------------------
// Main kernel, affine fast path:
//  - 8 elements per thread per iteration (2x dwordx4 per stream)
//  - all streaming traffic NON-TEMPORAL (keeps 4MB midx table L2-resident)
//  - 16 independent gathers into midx issued back-to-back (high MLP)
//  - arithmetic verify (no verify-gather); rare miss -> cold binary search
// ---------------------------------------------------------------------------
__global__ void __launch_bounds__(THREADS)
remap_main(const int* __restrict__ rv, const int* __restrict__ rk,
           const int* __restrict__ sc,
           const int* __restrict__ sids, const int* __restrict__ midx,
           const int* __restrict__ flagp,
           float* __restrict__ out_vals, float* __restrict__ out_keys,
           float* __restrict__ out_wts, int N, int V) {
    const int s0 = sids[0];
    const int sL = sids[V - 1];
    const long long range = (long long)sL - (long long)s0;
    const int affine = (*flagp == 0);
    const int step = (affine && V > 1) ? (int)(range / (long long)(V - 1)) : 1;
    const double inv_step = 1.0 / (double)step;
    const double scale = (range > 0) ? ((double)(V - 1) / (double)range) : 0.0;

    const int t = blockIdx.x * blockDim.x + threadIdx.x;
    const int T = gridDim.x * blockDim.x;
    const int N8 = N >> 3;

    if (affine) {
        const iv4* __restrict__ rv4 = (const iv4*)rv;
        const iv4* __restrict__ rk4 = (const iv4*)rk;
        const iv4* __restrict__ sc4 = (const iv4*)sc;
        for (int idx = t; idx < N8; idx += T) {
            iv4 va = __builtin_nontemporal_load(&rv4[2 * idx]);
            iv4 vb = __builtin_nontemporal_load(&rv4[2 * idx + 1]);
            iv4 ka = __builtin_nontemporal_load(&rk4[2 * idx]);
            iv4 kb = __builtin_nontemporal_load(&rk4[2 * idx + 1]);
            iv4 wa = __builtin_nontemporal_load(&sc4[2 * idx]);
            iv4 wb = __builtin_nontemporal_load(&sc4[2 * idx + 1]);

            // 16 positions (register-only arithmetic)
            int pv0 = aff_guess(va.x, s0, inv_step, V);
            int pv1 = aff_guess(va.y, s0, inv_step, V);
            int pv2 = aff_guess(va.z, s0, inv_step, V);
            int pv3 = aff_guess(va.w, s0, inv_step, V);
            int pv4 = aff_guess(vb.x, s0, inv_step, V);
            int pv5 = aff_guess(vb.y, s0, inv_step, V);
            int pv6 = aff_guess(vb.z, s0, inv_step, V);
            int pv7 = aff_guess(vb.w, s0, inv_step, V);
            int pk0 = aff_guess(ka.x, s0, inv_step, V);
            int pk1 = aff_guess(ka.y, s0, inv_step, V);
            int pk2 = aff_guess(ka.z, s0, inv_step, V);
            int pk3 = aff_guess(ka.w, s0, inv_step, V);
            int pk4 = aff_guess(kb.x, s0, inv_step, V);
            int pk5 = aff_guess(kb.y, s0, inv_step, V);
            int pk6 = aff_guess(kb.z, s0, inv_step, V);
            int pk7 = aff_guess(kb.w, s0, inv_step, V);

            // 16 independent gathers into the (L2-resident) midx table
            int m0 = midx[pv0];
            int m1 = midx[pv1];
            int m2 = midx[pv2];
            int m3 = midx[pv3];
            int m4 = midx[pv4];
            int m5 = midx[pv5];
            int m6 = midx[pv6];
            int m7 = midx[pv7];
            int n0 = midx[pk0];
            int n1 = midx[pk1];
            int n2 = midx[pk2];
            int n3 = midx[pk3];
            int n4 = midx[pk4];
            int n5 = midx[pk5];
            int n6 = midx[pk6];
            int n7 = midx[pk7];

            // arithmetic verify; cold fix never taken when all ids hit
            if (va.x != s0 + pv0 * step) m0 = cold_lookup(va.x, sids, midx, V);
            if (va.y != s0 + pv1 * step) m1 = cold_lookup(va.y, sids, midx, V);
            if (va.z != s0 + pv2 * step) m2 = cold_lookup(va.z, sids, midx, V);
            if (va.w != s0 + pv3 * step) m3 = cold_lookup(va.w, sids, midx, V);
            if (vb.x != s0 + pv4 * step) m4 = cold_lookup(vb.x, sids, midx, V);
            if (vb.y != s0 + pv5 * step) m5 = cold_lookup(vb.y, sids, midx, V);
            if (vb.z != s0 + pv6 * step) m6 = cold_lookup(vb.z, sids, midx, V);
            if (vb.w != s0 + pv7 * step) m7 = cold_lookup(vb.w, sids, midx, V);
            if (ka.x != s0 + pk0 * step) n0 = cold_lookup(ka.x, sids, midx, V);
            if (ka.y != s0 + pk1 * step) n1 = cold_lookup(ka.y, sids, midx, V);
            if (ka.z != s0 + pk2 * step) n2 = cold_lookup(ka.z, sids, midx, V);
            if (ka.w != s0 + pk3 * step) n3 = cold_lookup(ka.w, sids, midx, V);
            if (kb.x != s0 + pk4 * step) n4 = cold_lookup(kb.x, sids, midx, V);
            if (kb.y != s0 + pk5 * step) n5 = cold_lookup(kb.y, sids, midx, V);
            if (kb.z != s0 + pk6 * step) n6 = cold_lookup(kb.z, sids, midx, V);
            if (kb.w != s0 + pk7 * step) n7 = cold_lookup(kb.w, sids, midx, V);

            const int base = idx << 3;
            __builtin_nontemporal_store((float)m0, &out_vals[base + 0]);
            __builtin_nontemporal_store((float)m1, &out_vals[base + 1]);
            __builtin_nontemporal_store((float)m2, &out_vals[base + 2]);
            __builtin_nontemporal_store((float)m3, &out_vals[base + 3]);
            __builtin_nontemporal_store((float)m4, &out_vals[base + 4]);
            __builtin_nontemporal_store((float)m5, &out_vals[base + 5]);
            __builtin_nontemporal_store((float)m6, &out_vals[base + 6]);
            __builtin_nontemporal_store((float)m7, &out_vals[base + 7]);
            __builtin_nontemporal_store((float)n0, &out_keys[base + 0]);
            __builtin_nontemporal_store((float)n1, &out_keys[base + 1]);
            __builtin_nontemporal_store((float)n2, &out_keys[base + 2]);
            __builtin_nontemporal_store((float)n3, &out_keys[base + 3]);
            __builtin_nontemporal_store((float)n4, &out_keys[base + 4]);
            __builtin_nontemporal_store((float)n5, &out_keys[base + 5]);
            __builtin_nontemporal_store((float)n6, &out_keys[base + 6]);
            __builtin_nontemporal_store((float)n7, &out_keys[base + 7]);
            __builtin_nontemporal_store(__int_as_float(wa.x), &out_wts[base + 0]);
            __builtin_nontemporal_store(__int_as_float(wa.y), &out_wts[base + 1]);
            __builtin_nontemporal_store(__int_as_float(wa.z), &out_wts[base + 2]);
            __builtin_nontemporal_store(__int_as_float(wa.w), &out_wts[base + 3]);
            __builtin_nontemporal_store(__int_as_float(wb.x), &out_wts[base + 4]);
            __builtin_nontemporal_store(__int_as_float(wb.y), &out_wts[base + 5]);
            __builtin_nontemporal_store(__int_as_float(wb.z), &out_wts[base + 6]);
            __builtin_nontemporal_store(__int_as_float(wb.w), &out_wts[base + 7]);
        }
        // tail (N % 8 != 0) — scalar
        for (int i = (N8 << 3) + t; i < N; i += T) {
            int x = rv[i], y = rk[i], wv = sc[i];
            int p = aff_guess(x, s0, inv_step, V);
            int q = aff_guess(y, s0, inv_step, V);
            int m = (x == s0 + p * step) ? midx[p] : cold_lookup(x, sids, midx, V);
            int n = (y == s0 + q * step) ? midx[q] : cold_lookup(y, sids, midx, V);
            out_vals[i] = (float)m;
            out_keys[i] = (float)n;
            out_wts[i]  = __int_as_float(wv);
        }
    } else {
        // general sorted table — exact semantics, scalar
        for (int i = t; i < N; i += T) {
            int x = rv[i], y = rk[i], wv = sc[i];
            out_vals[i] = (float)remap_general(x, sids, midx, V, s0, scale);
            out_keys[i] = (float)remap_general(y, sids, midx, V, s0, scale);
            out_wts[i]  = __int_as_float(wv);
        }
    }
}

__global__ void copy_offsets(const int* __restrict__ off, float* __restrict__ o1,
                             float* __restrict__ o2, int n) {
    int i = blockIdx.x * blockDim.x + threadIdx.x;
    if (i < n) {
        float v = (float)off[i];
        o1[i] = v;
        o2[i] = v;
    }
}

extern "C" void kernel_launch(void* const* d_in, const int* in_sizes, int n_in,
                              void* d_out, int out_size, void* d_ws, size_t ws_size,
                              hipStream_t stream) {
    const int* rv   = (const int*)d_in[0];   // raw_values  (N)
    const int* rk   = (const int*)d_in[1];   // raw_keys    (N)
    const int* sc   = (const int*)d_in[2];   // scores      (N, f32 bits)
    const int* off  = (const int*)d_in[3];   // offsets     (B+1)
    const int* sids = (const int*)d_in[4];   // sorted_ids  (V)
    const int* midx = (const int*)d_in[5];   // mapped_idx  (V)

    const int N    = in_sizes[0];
    const int Boff = in_sizes[3];            // B + 1
    const int V    = in_sizes[4];

    // Output tuple layout (flat f32 words):
    // [offsets | idx_values | offsets | idx_keys | weights]
    float* out    = (float*)d_out;
    float* o_off1 = out;
    float* o_vals = out + Boff;
    float* o_off2 = out + Boff + N;
    float* o_keys = out + 2 * Boff + N;
    float* o_wts  = out + 2 * Boff + 2 * N;

    int* flag = (int*)d_ws;                  // ws[0]: 0 = affine, 1 = not
    (void)hipMemsetAsync(flag, 0, sizeof(int), stream);
    check_affine<<<1024, THREADS, 0, stream>>>(sids, V, flag);

    // 8 elements/thread: 8192 blocks x 256 threads x 8 = 16.7M in one pass
    remap_main<<<8192, THREADS, 0, stream>>>(rv, rk, sc, sids, midx, flag,
                                             o_vals, o_keys, o_wts, N, V);

    copy_offsets<<<(Boff + THREADS - 1) / THREADS, THREADS, 0, stream>>>(off, o_off1, o_off2, Boff);
}